// Round 10
// baseline (257.118 us; speedup 1.0000x reference)
//
#include <hip/hip_runtime.h>

// Problem constants (match reference)
#define C 80
#define P 30000
#define G 800
#define BS 256
#define NB 16           // 64-px cells over [0,1024); boxes binned by CENTER
#define NC (NB * NB)    // 256 cells per class
#define PPTM 8          // sorted slots per thread in match
#define TPBM (BS * PPTM)// 2048 sorted slots per match block
#define HCH 8           // hist chunks per class (finale parallelism)
#define CHSZ ((P + HCH - 1) / HCH)   // 3750

// Center-binning prune (validated absmax 0.0 across rounds 1-5,7-9): IoU>0.5
// forces each box to contain the other's center in both dims, so any viable
// GT's center lies strictly inside the pred box -> candidate cells are
// exactly the cells the pred box overlaps. Pruned pairs provably have
// IoU <= 0.5; validity re-verified with the bit-exact reference division.
//
// Round-10: rounds 8-9 proved match is VALU-ISSUE bound with a ~3x
// divergence multiplier (4 preds/cell in the block-local sort -> a wave
// spans ~16 cells -> per-lane loop bounds, max-trip ~40 vs mean 13; FETCH
// dropped 3x with no time change). Fix: GLOBAL per-class cell sort (ushort
// indices only — round-3's lesson: don't materialize records) -> a wave's
// 64 lanes sit in 1-2 cells (~117 preds/cell): uniform trips, broadcast
// LDS, near-uniform bounds. Pred rows gathered from global in match are
// L3-resident (67MB, streamed by pprep the launch before). Plumbing =
// verbatim-proven round-2 pieces; scan folded into pscatter redundantly.
//
// Round-7 lesson kept everywhere: atomically-accumulated buffers (predCnt,
// gHist) cross a KERNEL BOUNDARY before being plain-read (XCD coherence).

// rank order = score desc, then pred-index asc. Packed key is monotone in
// that order (scores >= 0 so float bits are order-preserving). key==0 means
// "no match" (needs score==0.0f AND p==P-1 — probability ~0).
__device__ __forceinline__ unsigned long long pack_key(float s, int p) {
    return ((unsigned long long)__float_as_uint(s) << 32) | (unsigned)(P - 1 - p);
}

__device__ __forceinline__ int cell_coord(float v) {
    return min(max((int)(v * (1.0f / 64.0f)), 0), NB - 1);
}

__device__ __forceinline__ int cell_of_center(float cxf, float cyf) {
    return cell_coord(cyf) * NB + cell_coord(cxf);
}

// ---------------- gt binning: one block per class (count+scan+scatter) ------
// (round-8 verbatim + predCnt/predCur zeroing.) BS == NC == 256: thread t
// owns cell t. Zeroes this class's gtKey, gHist, predCnt, predCur, ticket.
__global__ __launch_bounds__(BS) void gt_bin_kernel(
        const float* __restrict__ gt,
        unsigned short* __restrict__ gtCnt, unsigned short* __restrict__ gtOff,
        float4* __restrict__ gtBox, float* __restrict__ gtAbe,
        unsigned short* __restrict__ gtIdx,
        unsigned long long* __restrict__ gtKey, int* __restrict__ gHist,
        int* __restrict__ predCnt, int* __restrict__ predCur,
        unsigned int* __restrict__ doneCnt) {
    __shared__ int h[NC], cur[NC];
    __shared__ int gcell[G];
    const int c = blockIdx.x, tid = threadIdx.x;
    h[tid] = 0;
    predCnt[c * NC + tid] = 0;                                       // folded init
    predCur[c * NC + tid] = 0;                                       // folded init
    if (c == 0 && tid == 0) *doneCnt = 0u;                           // folded init
    for (int i = tid; i < G; i += BS) gtKey[c * G + i] = 0ull;       // folded init
    for (int j = tid; j < 1024; j += BS) gHist[c * 1024 + j] = 0;    // folded init
    __syncthreads();
    for (int i = tid; i < G; i += BS) {
        const float* r = gt + ((size_t)c * G + i) * 7;
        int cl = cell_of_center(0.5f * (r[3] + r[5]), 0.5f * (r[4] + r[6]));
        gcell[i] = cl;
        atomicAdd(&h[cl], 1);
    }
    __syncthreads();
    const int v = h[tid];
    cur[tid] = v;
    __syncthreads();
    for (int o = 1; o < NC; o <<= 1) {   // inclusive scan, 8 steps
        int t = (tid >= o) ? cur[tid - o] : 0;
        __syncthreads();
        cur[tid] += t;
        __syncthreads();
    }
    const int excl = cur[tid] - v;
    gtOff[c * NC + tid] = (unsigned short)excl;
    gtCnt[c * NC + tid] = (unsigned short)v;
    __syncthreads();
    cur[tid] = excl;
    __syncthreads();
    for (int i = tid; i < G; i += BS) {
        const float* r = gt + ((size_t)c * G + i) * 7;   // L1-hot (2nd pass)
        float x1 = r[3], y1 = r[4], x2 = r[5], y2 = r[6];
        int slot = atomicAdd(&cur[gcell[i]], 1);
        gtBox[c * G + slot] = make_float4(x1, y1, x2, y2);
        // area + eps pre-folded: cross-compare uses sb = A + (area_g + eps);
        // the -inter terms of the two denominators cancel algebraically.
        gtAbe[c * G + slot] = __fadd_rn(__fmul_rn(__fsub_rn(x2, x1), __fsub_rn(y2, y1)), 1e-9f);
        gtIdx[c * G + slot] = (unsigned short)i;
    }
}

// ---------------- pprep: per-(class,cell) counts + cell cache ----------
// (round-2 pred_prep verbatim, minus scoreC.) Also streams the whole pred
// slab through L3, priming it for match10's gather two launches later.
__global__ __launch_bounds__(BS) void pprep_kernel(
        const float* __restrict__ pred, int* __restrict__ predCnt,
        unsigned char* __restrict__ cellB) {
    __shared__ int h[NC];
    const int c = blockIdx.y, tid = threadIdx.x;
    h[tid] = 0;
    __syncthreads();
    int p = blockIdx.x * BS + tid;
    if (p < P) {
        const float* r = pred + ((size_t)c * P + p) * 7;
        int cl = cell_of_center(0.5f * (r[3] + r[5]), 0.5f * (r[4] + r[6]));
        cellB[(size_t)c * P + p] = (unsigned char)cl;   // NC==256 fits uchar
        atomicAdd(&h[cl], 1);
    }
    __syncthreads();
    if (h[tid]) atomicAdd(&predCnt[c * NC + tid], h[tid]);   // no-return
}

// ---------------- pscatter: cell-sorted ushort index scatter ----------
// Reads cellB coalesced (round-2 scatter pattern). The 256-bin exclusive
// scan of predCnt is computed REDUNDANTLY per block (8-step LDS scan, ~1us
// aggregate) — predCnt was finalized in the PREVIOUS launch (coherence-safe
// plain reads); slot reservation via device atomics on predCur (zeroed in
// gt_bin). Intra-cell order is arbitrary — match's argmax is keyed by GT
// index and atomicMax is order-free (proven rounds 0/3).
__global__ __launch_bounds__(BS) void pscatter_kernel(
        const unsigned char* __restrict__ cellB, const int* __restrict__ predCnt,
        int* __restrict__ predCur, unsigned short* __restrict__ pIdxS) {
    __shared__ int h[NC], base[NC], sc[NC];
    const int c = blockIdx.y, tid = threadIdx.x;
    h[tid] = 0;
    sc[tid] = predCnt[c * NC + tid];
    const int v = sc[tid];
    __syncthreads();
    int p = blockIdx.x * BS + tid;
    int cellv = 0, lr = 0;
    if (p < P) {
        cellv = cellB[(size_t)c * P + p];
        lr = atomicAdd(&h[cellv], 1);   // LDS, local rank
    }
    __syncthreads();
    for (int o = 1; o < NC; o <<= 1) {  // inclusive scan (proven pattern)
        int t = (tid >= o) ? sc[tid - o] : 0;
        __syncthreads();
        sc[tid] += t;
        __syncthreads();
    }
    if (h[tid]) base[tid] = (sc[tid] - v) + atomicAdd(&predCur[c * NC + tid], h[tid]);
    __syncthreads();
    if (p < P) pIdxS[(size_t)c * P + base[cellv] + lr] = (unsigned short)p;
}

// ---------------- match: wave-coherent sorted slots, GT in LDS ----------
// Block covers TPBM consecutive SORTED slots: a wave's 64 lanes sit in 1-2
// cells (~117 preds/cell) -> uniform trip counts, broadcast LDS reads,
// near-uniform bounds. Pred rows gathered from global (L3-hot). Pair
// arithmetic, GT order, and the bit-exact epilogue verbatim from the proven
// rounds 2-9 kernels; box-overlap candidate prune verbatim from round 8.
__global__ __launch_bounds__(BS) void match10_kernel(
        const float* __restrict__ pred, const unsigned short* __restrict__ pIdxS,
        const unsigned short* __restrict__ gtOff, const unsigned short* __restrict__ gtCnt,
        const float4* __restrict__ gtBox, const float* __restrict__ gtAbe,
        const unsigned short* __restrict__ gtIdx,
        unsigned long long* __restrict__ gtKey) {
    __shared__ float4 sB[G];                        // 12.8 KB
    __shared__ float  sE[G];                        //  3.2 KB
    __shared__ unsigned short sG[G];                //  1.6 KB
    __shared__ unsigned short sOff[NC], sCnt[NC];   //  1.0 KB => 18.6 KB
    const int c = blockIdx.y, tid = threadIdx.x;
    const int s0 = blockIdx.x * TPBM;

    for (int i = tid; i < G; i += BS) {
        sB[i] = gtBox[c * G + i];
        sE[i] = gtAbe[c * G + i];
        sG[i] = gtIdx[c * G + i];
    }
    sOff[tid] = gtOff[c * NC + tid];   // BS == NC
    sCnt[tid] = gtCnt[c * NC + tid];
    __syncthreads();

    const size_t cp = (size_t)c * P;
    #pragma unroll 1
    for (int rep = 0; rep < PPTM; ++rep) {
        const int slot = s0 + rep * BS + tid;
        if (slot < P) {
            const int p = pIdxS[cp + slot];           // coalesced ushort
            const float* r = pred + (cp + p) * 7;     // L3-hot gather
            float ax1 = r[3], ay1 = r[4], ax2 = r[5], ay2 = r[6];
            float A = __fmul_rn(__fsub_rn(ax2, ax1), __fsub_rn(ay2, ay1));
            // candidate cells: those the pred box overlaps (any GT center
            // with iou>0.5 lies strictly inside the pred box)
            const int x0 = cell_coord(ax1), x1 = cell_coord(ax2);
            const int y0 = cell_coord(ay1), y1 = cell_coord(ay2);
            float IN = 0.0f, SB = 1.0f;
            int mj = -1;
            for (int yy = y0; yy <= y1; ++yy) {
                const int rowb = yy * NB;
                const int jb = sOff[rowb + x0];
                const int je = sOff[rowb + x1] + sCnt[rowb + x1];
                #pragma unroll 2
                for (int j = jb; j < je; ++j) {
                    float4 b = sB[j];
                    float lx = fmaxf(ax1, b.x), ly = fmaxf(ay1, b.y);
                    float rx = fminf(ax2, b.z), ry = fminf(ay2, b.w);
                    float wx = fmaxf(__fsub_rn(rx, lx), 0.0f);
                    float wy = fmaxf(__fsub_rn(ry, ly), 0.0f);
                    float in = __fmul_rn(wx, wy);
                    float sb = __fadd_rn(A, sE[j]);
                    bool  up = __fmul_rn(in, SB) > __fmul_rn(IN, sb);
                    IN = up ? in : IN; SB = up ? sb : SB; mj = up ? j : mj;
                }
            }
            if (IN > 0.0f) {   // zero-inter preds can never be valid
                float4 b = sB[mj];
                float area = __fmul_rn(__fsub_rn(b.z, b.x), __fsub_rn(b.w, b.y));
                float dn = __fadd_rn(__fsub_rn(__fadd_rn(A, area), IN), 1e-9f);
                float iou = __fdiv_rn(IN, dn);   // exact reference value
                if (iou > 0.5f) {
                    float sscore = r[2];         // rare path
                    atomicMax(&gtKey[c * G + sG[mj]], pack_key(sscore, p));
                }
            }
        }
    }
}

// ---------------- histf: compact+sort (x8 redundant) + chunked hist ------
// (verbatim round 8 — passed.) gHist consumed only in the NEXT launch.
__global__ __launch_bounds__(BS) void histf_kernel(
        const float* __restrict__ pred,
        const unsigned long long* __restrict__ gtKey,
        int* __restrict__ gHist, int* __restrict__ sortT) {
    __shared__ unsigned long long k[G];     // 6.4 KB compacted keys
    __shared__ unsigned long long sk[1024]; // 8 KB sorted-desc keys (pad=0)
    __shared__ int h[1024];                 // 4 KB local hist
    __shared__ int cnt;
    const int c = blockIdx.y, chunk = blockIdx.x, tid = threadIdx.x;

    if (tid == 0) cnt = 0;
    for (int j = tid; j < 1024; j += BS) { sk[j] = 0ull; h[j] = 0; }
    __syncthreads();
    for (int i = tid; i < G; i += BS) {
        unsigned long long key = gtKey[c * G + i];
        if (key != 0ull) k[atomicAdd(&cnt, 1)] = key;
    }
    __syncthreads();
    const int T = cnt;
    if (chunk == 0 && tid == 0) sortT[c] = T;

    for (int t = tid; t < T; t += BS) {
        unsigned long long key = k[t];
        int pos = 0;
        for (int u = 0; u < T; ++u) pos += (k[u] > key) ? 1 : 0;
        sk[pos] = key;
    }
    __syncthreads();

    const int start = chunk * CHSZ;
    const int end   = min(start + CHSZ, P);
    const float* pr = pred + (size_t)c * P * 7;
    for (int i = start + tid; i < end; i += BS) {
        unsigned long long kq =
            ((unsigned long long)__float_as_uint(pr[(size_t)i * 7 + 2]) << 32)
            | (unsigned)(P - 1 - i);
        int lo = 0;   // count of sorted-desc keys > kq (pads are 0, never > kq)
        #pragma unroll
        for (int step = 512; step > 0; step >>= 1)
            if (sk[lo + step - 1] > kq) lo += step;
        atomicAdd(&h[lo], 1);
    }
    __syncthreads();
    for (int j = tid; j < 1024; j += BS)
        if (h[j]) atomicAdd(&gHist[c * 1024 + j], h[j]);   // no-return
}

// ---------------- ap + mean: prefix over hist + closed-form + last-block ----
// (verbatim round 8 — passed.)
__global__ __launch_bounds__(BS) void ap2m_kernel(
        const int* __restrict__ sortT, const int* __restrict__ gHist,
        float* __restrict__ ap, unsigned int* __restrict__ doneCnt,
        float* __restrict__ out) {
    __shared__ int ha[1024];
    __shared__ int hb[1024];
    __shared__ float red[BS];
    const int c = blockIdx.x, tid = threadIdx.x;
    const int T = sortT[c];
    for (int j = tid; j < 1024; j += BS) ha[j] = gHist[c * 1024 + j];
    __syncthreads();
    int* src = ha; int* dst = hb;
    for (int o = 1; o < 1024; o <<= 1) {
        for (int j = tid; j < 1024; j += BS)
            dst[j] = src[j] + ((j >= o) ? src[j - o] : 0);
        __syncthreads();
        int* tmp = src; src = dst; dst = tmp;
    }
    float sum = 0.0f;
    for (int s = tid; s < T; s += BS) {
        int r = src[s] - 1;          // inclusive prefix minus self
        if (r >= 1) {
            float kf  = (float)(s + 1);
            float km  = (float)s;
            float ri  = __fdiv_rn(kf, 800.0f);
            float rim = __fdiv_rn(km, 800.0f);
            float pi  = __fdiv_rn(kf, (float)(r + 1));
            float pim = __fdiv_rn(km, (float)r);
            sum = __fadd_rn(sum,
                  __fmul_rn(__fmul_rn(__fsub_rn(ri, rim), __fadd_rn(pi, pim)), 0.5f));
        }
    }
    red[tid] = sum;
    __syncthreads();
    for (int s2 = BS / 2; s2 > 0; s2 >>= 1) {
        if (tid < s2) red[tid] = __fadd_rn(red[tid], red[tid + s2]);
        __syncthreads();
    }
    if (tid == 0) {
        ap[c] = red[0];
        __threadfence();                         // publish ap[c] device-wide
        unsigned int t = atomicAdd(doneCnt, 1u); // ticket
        if (t == C - 1) {                        // last block finishes the mean
            __threadfence();                     // acquire all ap[] writes
            float s = 0.0f;
            for (int c2 = 0; c2 < C; ++c2) s = __fadd_rn(s, ap[c2]);
            out[0] = __fdiv_rn(s, 80.0f);
        }
    }
}

extern "C" void kernel_launch(void* const* d_in, const int* in_sizes, int n_in,
                              void* d_out, int out_size, void* d_ws, size_t ws_size,
                              hipStream_t stream) {
    const float* pred = (const float*)d_in[0];   // [C, P, 7] f32
    const float* gt   = (const float*)d_in[1];   // [C, G, 7] f32
    float* out = (float*)d_out;

    // Workspace layout — 9,694,464 B total (well under the proven 24.7 MB).
    // Re-poisoned 0xAA each call — gt_bin (incl. folded inits: gtKey, gHist,
    // predCnt, predCur, doneCnt) / pprep (cellB) / pscatter (pIdxS) rewrite
    // everything read-before-write.
    char* ws = (char*)d_ws;
    int*                sortT      = (int*)               (ws + 0);         //     320 B
    float*              ap         = (float*)             (ws + 512);       //     320 B
    unsigned int*       doneCnt    = (unsigned int*)      (ws + 896);       //       4 B
    int*                predCnt    = (int*)               (ws + 1024);      //  81920 B
    int*                predCur    = (int*)               (ws + 82944);     //  81920 B
    unsigned short*     gtCnt      = (unsigned short*)    (ws + 164864);    //  40960 B
    unsigned short*     gtOff      = (unsigned short*)    (ws + 205824);    //  40960 B
    unsigned short*     gtIdx      = (unsigned short*)    (ws + 246784);    // 128000 B
    float*              gtAbe      = (float*)             (ws + 374784);    // 256000 B
    float4*             gtBox      = (float4*)            (ws + 630784);    // 1.024 MB (16-aligned)
    unsigned long long* gtKey      = (unsigned long long*)(ws + 1654784);   // 512000 B
    int*                gHist      = (int*)               (ws + 2166784);   // 327680 B
    unsigned char*      cellB      = (unsigned char*)     (ws + 2494464);   // 2.4 MB
    unsigned short*     pIdxS      = (unsigned short*)    (ws + 4894464);   // 4.8 MB
    // end: 9694464 B

    const int P_BLK = (P + BS - 1) / BS;       // 118
    const int M_BLK = (P + TPBM - 1) / TPBM;   // 15

    gt_bin_kernel<<<C, BS, 0, stream>>>(gt, gtCnt, gtOff, gtBox, gtAbe, gtIdx,
                                        gtKey, gHist, predCnt, predCur, doneCnt);
    pprep_kernel<<<dim3(P_BLK, C), BS, 0, stream>>>(pred, predCnt, cellB);
    pscatter_kernel<<<dim3(P_BLK, C), BS, 0, stream>>>(cellB, predCnt, predCur, pIdxS);
    match10_kernel<<<dim3(M_BLK, C), BS, 0, stream>>>(pred, pIdxS, gtOff, gtCnt,
                                                      gtBox, gtAbe, gtIdx, gtKey);
    histf_kernel<<<dim3(HCH, C), BS, 0, stream>>>(pred, gtKey, gHist, sortT);
    ap2m_kernel<<<C, BS, 0, stream>>>(sortT, gHist, ap, doneCnt, out);
}